// Round 7
// baseline (52511.053 us; speedup 1.0000x reference)
//
#include <hip/hip_runtime.h>

#define SEQ 256

// ---- ws layout (float offsets) ----
#define WL0     0u           // lstm0 fused W' [c=j*4+g][k=1024] (k<512: wih, else whh)
#define WL1     2097152u     // lstm1 fused W'
#define FCT     4194304u     // fc_w^T [k=256][n=2048]
#define OFF_FC  4718592u     // FCIN double buffer [2][256][2048] (map layout)
#define OFF_XM  5767168u     // sigmoid(map) [256][512]
#define OFF_X0  5898240u     // raw h2 of layer0 [256][512]
#define OFF_ARR 6029312u     // flag-array barrier: 256 slots x 32-float stride (128B)
// end 6037504 floats = 24.2 MB

// ---- LDS float offsets (512-thread layout) ----
// A tile: [128 k][68], col = c ^ phi(k), phi(k) = ((k>>2)&7)<<2
// W tile: [128 k][36], same swizzle
#define S_AS0 0
#define S_WS0 8704
#define S_AS1 13312
#define S_WS1 22016          // ends 26624
#define S_RED 13312          // 512*33 = 16896 partials (aliases buf1; last chunk uses buf0)
#define S_GS  30208          // 32*65 = 2080 gate exchange
#define S_TOT 32288          // 129152 B <= 160 KB/CU, 1 block/CU

__device__ __forceinline__ float sigf(float x){ return 1.0f/(1.0f + __expf(-x)); }
__device__ __forceinline__ float tanhf_(float x){
  float cx = fminf(fmaxf(x, -15.f), 15.f);
  float e = __expf(2.f*cx);
  return (e-1.f)/(e+1.f);
}

// ---------- one-time: transpose fc_w -> FCT[k][n] ----------
__global__ __launch_bounds__(256) void tr_kernel(const float* __restrict__ src,
                                                 float* __restrict__ dst, int R, int C){
  int i = blockIdx.x*256 + threadIdx.x;
  if (i < R*C){ int r = i / C, c = i - r*C; dst[(size_t)c*R + r] = src[i]; }
}

// ---------- one-time: build fused gate-interleaved LSTM weights ----------
__global__ __launch_bounds__(256) void wprep(const float* __restrict__ wih0,
                                             const float* __restrict__ whh0,
                                             const float* __restrict__ wih1,
                                             const float* __restrict__ whh1,
                                             float* __restrict__ ws){
  const unsigned idx = blockIdx.x*256u + threadIdx.x;
  const unsigned layer = idx >> 21, rem = idx & 2097151u;
  const unsigned c = rem >> 10, k = rem & 1023u;
  const unsigned j = c >> 2, g = c & 3u;
  const float* wih = layer ? wih1 : wih0;
  const float* whh = layer ? whh1 : whh0;
  const float v = (k < 512u) ? wih[(g*512u + j)*512u + k] : whh[(g*512u + j)*512u + (k - 512u)];
  ws[(layer ? WL1 : WL0) + rem] = v;
}

// ---------- init: dec=tanh(latent@fc_w.T+fc_b) scattered into FCIN[0] map layout ----------
__global__ __launch_bounds__(256) void init2(const float* __restrict__ latent,
                                             const float* __restrict__ fc_b,
                                             float* __restrict__ ws){
  __shared__ float ls[256];
  const int b = blockIdx.x, tid = threadIdx.x;
  if (tid < 32)
    __hip_atomic_store((unsigned*)(ws + OFF_ARR) + b*32 + tid, 0u,
                       __ATOMIC_RELAXED, __HIP_MEMORY_SCOPE_AGENT);
  ls[tid] = latent[b*256 + tid];
  __syncthreads();
  const float* fT = ws + FCT;
  for (int nc = 0; nc < 8; ++nc){
    const int n = nc*256 + tid;
    float acc = fc_b[n];
    for (int k = 0; k < 256; ++k) acc += ls[k] * fT[k*2048 + n];
    const float v = tanhf_(acc);
    const unsigned f = (unsigned)b*2048u + (unsigned)n;
    const unsigned l = f >> 18, p = (f >> 10) & 255u, q = f & 1023u;
    ws[OFF_FC + (l*128u + (p>>1))*2048u + (p&1u)*1024u + q] = v;
  }
}

// ---------- flag-array grid barrier (R4-proven: parallel release stores + 1 acquire) ----
__device__ __forceinline__ void gsync(unsigned* arr, unsigned epoch, int tid, int blk){
  __syncthreads();                       // all waves' stores drained (vmcnt 0)
  if (tid == 0)
    __hip_atomic_store(arr + (unsigned)blk*32u, epoch,
                       __ATOMIC_RELEASE, __HIP_MEMORY_SCOPE_AGENT);
  if (tid < 64){
    unsigned m;
    do {
      const unsigned v0 = __hip_atomic_load(arr + (unsigned)(tid      )*32u, __ATOMIC_RELAXED, __HIP_MEMORY_SCOPE_AGENT);
      const unsigned v1 = __hip_atomic_load(arr + (unsigned)(tid +  64)*32u, __ATOMIC_RELAXED, __HIP_MEMORY_SCOPE_AGENT);
      const unsigned v2 = __hip_atomic_load(arr + (unsigned)(tid + 128)*32u, __ATOMIC_RELAXED, __HIP_MEMORY_SCOPE_AGENT);
      const unsigned v3 = __hip_atomic_load(arr + (unsigned)(tid + 192)*32u, __ATOMIC_RELAXED, __HIP_MEMORY_SCOPE_AGENT);
      const unsigned m01 = v0 < v1 ? v0 : v1;
      const unsigned m23 = v2 < v3 ? v2 : v3;
      m = m01 < m23 ? m01 : m23;
      if (m < epoch) __builtin_amdgcn_s_sleep(2);
    } while (!__all(m >= epoch));
  }
  __syncthreads();
  if (tid == 0) __builtin_amdgcn_fence(__ATOMIC_ACQUIRE, "agent");   // one inv per block
  __syncthreads();
}

__device__ __forceinline__ void fma8x4(float acc[8][4], const float4 A0, const float4 A1,
                                       const float4 W0){
  const float a_[8] = {A0.x,A0.y,A0.z,A0.w,A1.x,A1.y,A1.z,A1.w};
  const float w_[4] = {W0.x,W0.y,W0.z,W0.w};
  #pragma unroll
  for (int i=0;i<8;++i)
    #pragma unroll
    for (int j=0;j<4;++j) acc[i][j] = __builtin_fmaf(a_[i], w_[j], acc[i][j]);
}

// ---------- phase: map GEMM out[256,512] = sigmoid(FCIN @ map_w^T + b) ----------
// 512 thr: rg=tid&7 (8 row-groups), ng=(tid>>3)&1 (2 col-groups of 4), kg=tid>>4 (32 k-slices)
__device__ __forceinline__ void map_phase(float* sm, const float* __restrict__ FCc,
    const float* __restrict__ map_w, const float* __restrict__ map_b,
    float* __restrict__ XM, float* __restrict__ outp_t, int tid, int r0, int cb)
{
  const int rg = tid & 7;
  const int ng = (tid >> 3) & 1;
  const int kg = tid >> 4;
  const int n0 = cb * 8;
  float acc[8][4];
  #pragma unroll
  for (int i=0;i<8;++i){
    #pragma unroll
    for (int j=0;j<4;++j) acc[i][j]=0.f;
  }
  float4 va[4]; float4 vw;

  auto LOADS = [&](int ch){
    #pragma unroll
    for (int it=0; it<4; ++it){
      const int e = tid + it*512, r = e>>5, kq = e&31;
      va[it] = *(const float4*)&FCc[(unsigned)(r0+r)*2048u + (unsigned)(ch*128 + kq*4)];
    }
    if (tid < 256){ const int n = tid>>5, kq = tid&31;
      vw = *(const float4*)&map_w[(unsigned)(n0+n)*2048u + (unsigned)(ch*128 + kq*4)]; }
  };
  auto STORES = [&](int buf){
    float* A_ = sm + (buf ? S_AS1 : S_AS0);
    float* W_ = sm + (buf ? S_WS1 : S_WS0);
    #pragma unroll
    for (int it=0; it<4; ++it){
      const int e = tid + it*512, r = e>>5, kq = e&31;
      const int col = r ^ ((kq&7)<<2);           // phi(k)=((k>>2)&7)<<2
      A_[(kq*4+0)*68 + col] = va[it].x;
      A_[(kq*4+1)*68 + col] = va[it].y;
      A_[(kq*4+2)*68 + col] = va[it].z;
      A_[(kq*4+3)*68 + col] = va[it].w;
    }
    if (tid < 256){ const int n = tid>>5, kq = tid&31;
      const int col = n ^ ((kq&7)<<2);
      W_[(kq*4+0)*36 + col] = vw.x;
      W_[(kq*4+1)*36 + col] = vw.y;
      W_[(kq*4+2)*36 + col] = vw.z;
      W_[(kq*4+3)*36 + col] = vw.w; }
  };
  auto COMPUTE = [&](int buf){
    const float* A_ = sm + (buf ? S_AS1 : S_AS0);
    const float* W_ = sm + (buf ? S_WS1 : S_WS0);
    const int phi = (kg & 7) << 2;               // k>>2 == kg for k=kg*4+u, u<4
    const int ca0 = (rg*8) ^ phi, ca1 = ca0 ^ 4;
    const int cw = (ng*4) ^ phi;
    #pragma unroll
    for (int u=0; u<4; ++u){
      const int k = kg*4 + u;
      const float4 a0 = *(const float4*)&A_[k*68 + ca0];
      const float4 a1 = *(const float4*)&A_[k*68 + ca1];
      const float4 w0 = *(const float4*)&W_[k*36 + cw];
      fma8x4(acc, a0, a1, w0);
    }
  };

  LOADS(0); STORES(1);
  __syncthreads();
  #pragma unroll 1
  for (int ch = 0; ch < 16; ++ch){
    const int buf = (ch & 1) ^ 1;
    if (ch+1 < 16) LOADS(ch+1);
    COMPUTE(buf);
    if (ch+1 < 16) STORES(buf^1);
    __syncthreads();
  }
  // split-K reduction (32-way over kg) + epilogue
  float* red = sm + S_RED;
  #pragma unroll
  for (int i=0;i<8;++i){
    #pragma unroll
    for (int j=0;j<4;++j) red[tid*33 + i*4 + j] = acc[i][j];
  }
  __syncthreads();
  {
    const int o = tid;                  // 512 outputs: 64r x 8n
    const int r = o >> 3, nl = o & 7;
    float sum = 0.f;
    #pragma unroll
    for (int kk=0;kk<32;++kk)
      sum += red[((r>>3) + 8*(nl>>2) + 16*kk)*33 + (r&7)*4 + (nl&3)];
    const int n = n0 + nl;
    const float v = sigf(sum + map_b[n]);
    const unsigned off = (unsigned)(r0 + r)*512u + (unsigned)n;
    XM[off] = v;
    outp_t[off] = v;
  }
}

// ---------- phase: lstm layer GEMM + cell ----------
// 512 thr: rg=tid&7, ng=(tid>>3)&7 (8 col-groups of 4), kg=tid>>6 (8 k-slices of 16)
__device__ __forceinline__ void lstm_phase(float* sm, const int l,
    const float* __restrict__ WL, const float* __restrict__ xs,
    const float* __restrict__ FCc, float* __restrict__ FCn,
    float* __restrict__ X0, const float* __restrict__ bih, const float* __restrict__ bhh,
    int tid, int r0, int cb)
{
  const int rg = tid & 7;
  const int ng = (tid >> 3) & 7;
  const int kg = tid >> 6;
  const int c0 = cb * 32;
  float acc[8][4];
  #pragma unroll
  for (int i=0;i<8;++i){
    #pragma unroll
    for (int j=0;j<4;++j) acc[i][j]=0.f;
  }
  float4 va[4], vw4[2];

  auto LOADS = [&](int ch){
    if (ch < 4){                                     // x part (k<512)
      #pragma unroll
      for (int it=0; it<4; ++it){
        const int e = tid + it*512, r = e>>5, kq = e&31;
        va[it] = *(const float4*)&xs[(unsigned)(r0+r)*512u + (unsigned)(ch*128 + kq*4)];
      }
    } else {                                         // h part from FCIN map layout
      #pragma unroll
      for (int it=0; it<4; ++it){
        const int e = tid + it*512, r = e>>5, kq = e&31;
        const int b = r0 + r;
        const unsigned q = (unsigned)((ch-4)*128 + kq*4);
        va[it] = *(const float4*)&FCc[(unsigned)((l<<7) + (b>>1))*2048u + (unsigned)(b&1)*1024u + q];
      }
    }
    #pragma unroll
    for (int it=0; it<2; ++it){
      const int e = tid + it*512, n = e>>5, kq = e&31;
      vw4[it] = *(const float4*)&WL[(unsigned)(c0+n)*1024u + (unsigned)(ch*128 + kq*4)];
    }
  };
  auto STORES = [&](int buf){
    float* A_ = sm + (buf ? S_AS1 : S_AS0);
    float* W_ = sm + (buf ? S_WS1 : S_WS0);
    #pragma unroll
    for (int it=0; it<4; ++it){
      const int e = tid + it*512, r = e>>5, kq = e&31;
      const int col = r ^ ((kq&7)<<2);
      A_[(kq*4+0)*68 + col] = va[it].x;
      A_[(kq*4+1)*68 + col] = va[it].y;
      A_[(kq*4+2)*68 + col] = va[it].z;
      A_[(kq*4+3)*68 + col] = va[it].w;
    }
    #pragma unroll
    for (int it=0; it<2; ++it){
      const int e = tid + it*512, n = e>>5, kq = e&31;
      const int col = n ^ ((kq&7)<<2);
      W_[(kq*4+0)*36 + col] = vw4[it].x;
      W_[(kq*4+1)*36 + col] = vw4[it].y;
      W_[(kq*4+2)*36 + col] = vw4[it].z;
      W_[(kq*4+3)*36 + col] = vw4[it].w;
    }
  };
  auto COMPUTE = [&](int buf){
    const float* A_ = sm + (buf ? S_AS1 : S_AS0);
    const float* W_ = sm + (buf ? S_WS1 : S_WS0);
    #pragma unroll
    for (int u=0; u<16; ++u){
      const int k = kg*16 + u;
      const int s = (((kg<<2) + (u>>2)) & 7) << 2;  // phi(k)
      const int ca = (rg*8) ^ s;
      const int cw = (ng*4) ^ s;
      const float4 a0 = *(const float4*)&A_[k*68 + ca];
      const float4 a1 = *(const float4*)&A_[k*68 + (ca^4)];
      const float4 w0 = *(const float4*)&W_[k*36 + cw];
      fma8x4(acc, a0, a1, w0);
    }
  };

  LOADS(0); STORES(1);
  __syncthreads();
  #pragma unroll 1
  for (int ch = 0; ch < 8; ++ch){
    const int buf = (ch & 1) ^ 1;
    if (ch+1 < 8) LOADS(ch+1);
    COMPUTE(buf);
    if (ch+1 < 8) STORES(buf^1);
    __syncthreads();
  }

  // split-K reduction (8-way over kg) -> gate exchange
  float* red = sm + S_RED;
  float* gs  = sm + S_GS;
  #pragma unroll
  for (int i=0;i<8;++i){
    #pragma unroll
    for (int j=0;j<4;++j) red[tid*33 + i*4 + j] = acc[i][j];
  }
  __syncthreads();
  #pragma unroll
  for (int s=0;s<4;++s){
    const int o = tid + s*512;          // 2048 outputs: 64r x 32c
    const int r = o >> 5, c = o & 31;
    float sum = 0.f;
    #pragma unroll
    for (int kk=0;kk<8;++kk)
      sum += red[((r>>3) + 8*(c>>2) + 64*kk)*33 + (r&7)*4 + (c&3)];
    gs[c*65 + r] = sum;
  }
  __syncthreads();
  // cell update: one (row, j) state per thread (64 rows x 8 j = 512)
  const int r = tid & 63, j0 = tid >> 6;
  const int row = r0 + r;
  const unsigned srow = (unsigned)((l<<7) + (row>>1))*2048u + (unsigned)(row&1)*1024u;
  const int jg = cb*8 + j0;
  const float gi = gs[(j0*4+0)*65 + r] + bih[jg]       + bhh[jg];
  const float gf = gs[(j0*4+1)*65 + r] + bih[512+jg]   + bhh[512+jg];
  const float gg = gs[(j0*4+2)*65 + r] + bih[1024+jg]  + bhh[1024+jg];
  const float go = gs[(j0*4+3)*65 + r] + bih[1536+jg]  + bhh[1536+jg];
  const float cp = FCc[srow + 512u + (unsigned)jg];
  const float c2 = sigf(gf)*cp + sigf(gi)*tanhf_(gg);
  const float h2 = sigf(go)*tanhf_(c2);
  if (l == 0) X0[(unsigned)row*512u + (unsigned)jg] = h2;   // raw h2 feeds layer 1
  FCn[srow + (unsigned)jg]        = tanhf_(h2);             // carried h (tanh)
  FCn[srow + 512u + (unsigned)jg] = tanhf_(c2);             // carried c (tanh)
}

// ---------- persistent cooperative kernel: whole 256-step sequence ----------
// 512 thr = 8 waves = 2 waves/SIMD (R4-R6 ran 1 wave/SIMD -> 80% stall).
__launch_bounds__(512, 2)
__global__ void persist(const float* __restrict__ map_w, const float* __restrict__ map_b,
                        const float* __restrict__ bih0, const float* __restrict__ bhh0,
                        const float* __restrict__ bih1, const float* __restrict__ bhh1,
                        float* __restrict__ ws, float* __restrict__ outp)
{
  __shared__ float sm[S_TOT];
  const int tid = threadIdx.x;
  const int blk = blockIdx.x;
  // XCD-aware swizzle: per-XCD weight slice = 8 cb x (64+128+128)KB = 2.56MB < 4MB L2.
  const int cb = ((blk & 7) << 3) | ((blk >> 3) & 7);
  const int rb = blk >> 6;
  const int r0 = rb * 64;
  float* FC = ws + OFF_FC;
  float* XM = ws + OFF_XM;
  float* X0 = ws + OFF_X0;
  unsigned* arr = (unsigned*)(ws + OFF_ARR);
  unsigned nsync = 0;

  #pragma unroll 1
  for (int t = 0; t < SEQ; ++t){
    const unsigned cur = (unsigned)(t & 1);
    const float* FCc = FC + cur*524288u;
    float* FCn = FC + (cur^1u)*524288u;

    map_phase(sm, FCc, map_w, map_b, XM, outp + (size_t)t*131072u, tid, r0, cb);
    if (t == SEQ-1) break;                       // last step only needs the map output
    gsync(arr, ++nsync, tid, blk);
    lstm_phase(sm, 0, ws + WL0, XM, FCc, FCn, X0, bih0, bhh0, tid, r0, cb);
    gsync(arr, ++nsync, tid, blk);
    lstm_phase(sm, 1, ws + WL1, X0, FCc, FCn, X0, bih1, bhh1, tid, r0, cb);
    gsync(arr, ++nsync, tid, blk);
  }
}

extern "C" void kernel_launch(void* const* d_in, const int* in_sizes, int n_in,
                              void* d_out, int out_size, void* d_ws, size_t ws_size,
                              hipStream_t stream)
{
  (void)in_sizes; (void)n_in; (void)out_size; (void)ws_size;
  const float* latent = (const float*)d_in[0];
  const float* fc_w   = (const float*)d_in[1];
  const float* fc_b   = (const float*)d_in[2];
  const float* map_w  = (const float*)d_in[3];
  const float* map_b  = (const float*)d_in[4];
  const float* wih0   = (const float*)d_in[5];
  const float* whh0   = (const float*)d_in[6];
  const float* bih0   = (const float*)d_in[7];
  const float* bhh0   = (const float*)d_in[8];
  const float* wih1   = (const float*)d_in[9];
  const float* whh1   = (const float*)d_in[10];
  const float* bih1   = (const float*)d_in[11];
  const float* bhh1   = (const float*)d_in[12];
  float* ws = (float*)d_ws;
  float* outp = (float*)d_out;

  tr_kernel<<<2048,256,0,stream>>>(fc_w, ws + FCT, 2048, 256);
  wprep<<<16384,256,0,stream>>>(wih0, whh0, wih1, whh1, ws);
  init2<<<256,256,0,stream>>>(latent, fc_b, ws);

  void* args[8];
  args[0] = (void*)&map_w; args[1] = (void*)&map_b;
  args[2] = (void*)&bih0;  args[3] = (void*)&bhh0;
  args[4] = (void*)&bih1;  args[5] = (void*)&bhh1;
  args[6] = (void*)&ws;    args[7] = (void*)&outp;
  hipError_t e = hipLaunchCooperativeKernel((const void*)persist, dim3(256), dim3(512),
                                            args, 0, stream);
  if (e != hipSuccess){
    persist<<<dim3(256), dim3(512), 0, stream>>>(map_w, map_b, bih0, bhh0,
                                                 bih1, bhh1, ws, outp);
  }
}

// Round 9
// 52463.477 us; speedup vs baseline: 1.0009x; 1.0009x over previous
//
#include <hip/hip_runtime.h>

#define SEQ 256

// ---- ws layout (float offsets) ----
#define WL0     0u           // lstm0 fused W' [c=j*4+g][k=1024] (k<512: wih, else whh)
#define WL1     2097152u     // lstm1 fused W'
#define FCT     4194304u     // fc_w^T [k=256][n=2048]
#define OFF_FC  4718592u     // FCIN double buffer [2][256][2048] (map layout)
#define OFF_XM  5767168u     // sigmoid(map) [256][512]
#define OFF_X0  5898240u     // raw h2 of layer0 [256][512]
#define OFF_ARR 6029312u     // flag-array barrier: 256 slots x 32-float stride (128B)
// end 6037504 floats = 24.2 MB

// ---- LDS float offsets (512-thread layout) ----
// A tile: [128 k][68], col = c ^ phi(k), phi(k) = ((k>>2)&7)<<2
// W tile: [128 k][36], same swizzle
#define S_AS0 0
#define S_WS0 8704
#define S_AS1 13312
#define S_WS1 22016          // ends 26624
#define S_RED 13312          // 512*33 = 16896 partials (aliases buf1; last chunk uses buf0)
#define S_GS  30208          // 32*65 = 2080 gate exchange
#define S_TOT 32288          // 129152 B <= 160 KB/CU, 1 block/CU

__device__ __forceinline__ float sigf(float x){ return 1.0f/(1.0f + __expf(-x)); }
__device__ __forceinline__ float tanhf_(float x){
  float cx = fminf(fmaxf(x, -15.f), 15.f);
  float e = __expf(2.f*cx);
  return (e-1.f)/(e+1.f);
}

// ---------- one-time: transpose fc_w -> FCT[k][n] ----------
__global__ __launch_bounds__(256) void tr_kernel(const float* __restrict__ src,
                                                 float* __restrict__ dst, int R, int C){
  int i = blockIdx.x*256 + threadIdx.x;
  if (i < R*C){ int r = i / C, c = i - r*C; dst[(size_t)c*R + r] = src[i]; }
}

// ---------- one-time: build fused gate-interleaved LSTM weights ----------
__global__ __launch_bounds__(256) void wprep(const float* __restrict__ wih0,
                                             const float* __restrict__ whh0,
                                             const float* __restrict__ wih1,
                                             const float* __restrict__ whh1,
                                             float* __restrict__ ws){
  const unsigned idx = blockIdx.x*256u + threadIdx.x;
  const unsigned layer = idx >> 21, rem = idx & 2097151u;
  const unsigned c = rem >> 10, k = rem & 1023u;
  const unsigned j = c >> 2, g = c & 3u;
  const float* wih = layer ? wih1 : wih0;
  const float* whh = layer ? whh1 : whh0;
  const float v = (k < 512u) ? wih[(g*512u + j)*512u + k] : whh[(g*512u + j)*512u + (k - 512u)];
  ws[(layer ? WL1 : WL0) + rem] = v;
}

// ---------- init: dec=tanh(latent@fc_w.T+fc_b) scattered into FCIN[0] map layout ----------
__global__ __launch_bounds__(256) void init2(const float* __restrict__ latent,
                                             const float* __restrict__ fc_b,
                                             float* __restrict__ ws){
  __shared__ float ls[256];
  const int b = blockIdx.x, tid = threadIdx.x;
  if (tid < 32)
    __hip_atomic_store((unsigned*)(ws + OFF_ARR) + b*32 + tid, 0u,
                       __ATOMIC_RELAXED, __HIP_MEMORY_SCOPE_AGENT);
  ls[tid] = latent[b*256 + tid];
  __syncthreads();
  const float* fT = ws + FCT;
  for (int nc = 0; nc < 8; ++nc){
    const int n = nc*256 + tid;
    float acc = fc_b[n];
    for (int k = 0; k < 256; ++k) acc += ls[k] * fT[k*2048 + n];
    const float v = tanhf_(acc);
    const unsigned f = (unsigned)b*2048u + (unsigned)n;
    const unsigned l = f >> 18, p = (f >> 10) & 255u, q = f & 1023u;
    ws[OFF_FC + (l*128u + (p>>1))*2048u + (p&1u)*1024u + q] = v;
  }
}

// ---------- flag-array grid barrier (R4-proven: parallel release stores + 1 acquire) ----
__device__ __forceinline__ void gsync(unsigned* arr, unsigned epoch, int tid, int blk){
  __syncthreads();                       // all waves' stores drained (vmcnt 0)
  if (tid == 0)
    __hip_atomic_store(arr + (unsigned)blk*32u, epoch,
                       __ATOMIC_RELEASE, __HIP_MEMORY_SCOPE_AGENT);
  if (tid < 64){
    unsigned m;
    do {
      const unsigned v0 = __hip_atomic_load(arr + (unsigned)(tid      )*32u, __ATOMIC_RELAXED, __HIP_MEMORY_SCOPE_AGENT);
      const unsigned v1 = __hip_atomic_load(arr + (unsigned)(tid +  64)*32u, __ATOMIC_RELAXED, __HIP_MEMORY_SCOPE_AGENT);
      const unsigned v2 = __hip_atomic_load(arr + (unsigned)(tid + 128)*32u, __ATOMIC_RELAXED, __HIP_MEMORY_SCOPE_AGENT);
      const unsigned v3 = __hip_atomic_load(arr + (unsigned)(tid + 192)*32u, __ATOMIC_RELAXED, __HIP_MEMORY_SCOPE_AGENT);
      const unsigned m01 = v0 < v1 ? v0 : v1;
      const unsigned m23 = v2 < v3 ? v2 : v3;
      m = m01 < m23 ? m01 : m23;
      if (m < epoch) __builtin_amdgcn_s_sleep(2);
    } while (!__all(m >= epoch));
  }
  __syncthreads();
  if (tid == 0) __builtin_amdgcn_fence(__ATOMIC_ACQUIRE, "agent");   // one inv per block
  __syncthreads();
}

__device__ __forceinline__ void fma8x4(float acc[8][4], const float4 A0, const float4 A1,
                                       const float4 W0){
  const float a_[8] = {A0.x,A0.y,A0.z,A0.w,A1.x,A1.y,A1.z,A1.w};
  const float w_[4] = {W0.x,W0.y,W0.z,W0.w};
  #pragma unroll
  for (int i=0;i<8;++i)
    #pragma unroll
    for (int j=0;j<4;++j) acc[i][j] = __builtin_fmaf(a_[i], w_[j], acc[i][j]);
}

// ---------- phase: map GEMM out[256,512] = sigmoid(FCIN @ map_w^T + b) ----------
// 512 thr: rg=tid&7 (8 row-groups), ng=(tid>>3)&1 (2 col-groups of 4), kg=tid>>4 (32 k-slices)
__device__ __forceinline__ void map_phase(float* sm, const float* __restrict__ FCc,
    const float* __restrict__ map_w, const float* __restrict__ map_b,
    float* __restrict__ XM, float* __restrict__ outp_t, int tid, int r0, int cb)
{
  const int rg = tid & 7;
  const int ng = (tid >> 3) & 1;
  const int kg = tid >> 4;
  const int n0 = cb * 8;
  float acc[8][4];
  #pragma unroll
  for (int i=0;i<8;++i){
    #pragma unroll
    for (int j=0;j<4;++j) acc[i][j]=0.f;
  }
  float4 va[4]; float4 vw;

  auto LOADS = [&](int ch){
    #pragma unroll
    for (int it=0; it<4; ++it){
      const int e = tid + it*512, r = e>>5, kq = e&31;
      va[it] = *(const float4*)&FCc[(unsigned)(r0+r)*2048u + (unsigned)(ch*128 + kq*4)];
    }
    if (tid < 256){ const int n = tid>>5, kq = tid&31;
      vw = *(const float4*)&map_w[(unsigned)(n0+n)*2048u + (unsigned)(ch*128 + kq*4)]; }
  };
  auto STORES = [&](int buf){
    float* A_ = sm + (buf ? S_AS1 : S_AS0);
    float* W_ = sm + (buf ? S_WS1 : S_WS0);
    #pragma unroll
    for (int it=0; it<4; ++it){
      const int e = tid + it*512, r = e>>5, kq = e&31;
      const int col = r ^ ((kq&7)<<2);           // phi(k)=((k>>2)&7)<<2
      A_[(kq*4+0)*68 + col] = va[it].x;
      A_[(kq*4+1)*68 + col] = va[it].y;
      A_[(kq*4+2)*68 + col] = va[it].z;
      A_[(kq*4+3)*68 + col] = va[it].w;
    }
    if (tid < 256){ const int n = tid>>5, kq = tid&31;
      const int col = n ^ ((kq&7)<<2);
      W_[(kq*4+0)*36 + col] = vw.x;
      W_[(kq*4+1)*36 + col] = vw.y;
      W_[(kq*4+2)*36 + col] = vw.z;
      W_[(kq*4+3)*36 + col] = vw.w; }
  };
  auto COMPUTE = [&](int buf){
    const float* A_ = sm + (buf ? S_AS1 : S_AS0);
    const float* W_ = sm + (buf ? S_WS1 : S_WS0);
    const int phi = (kg & 7) << 2;               // k>>2 == kg for k=kg*4+u, u<4
    const int ca0 = (rg*8) ^ phi, ca1 = ca0 ^ 4;
    const int cw = (ng*4) ^ phi;
    #pragma unroll
    for (int u=0; u<4; ++u){
      const int k = kg*4 + u;
      const float4 a0 = *(const float4*)&A_[k*68 + ca0];
      const float4 a1 = *(const float4*)&A_[k*68 + ca1];
      const float4 w0 = *(const float4*)&W_[k*36 + cw];
      fma8x4(acc, a0, a1, w0);
    }
  };

  LOADS(0); STORES(1);
  __syncthreads();
  #pragma unroll 1
  for (int ch = 0; ch < 16; ++ch){
    const int buf = (ch & 1) ^ 1;
    if (ch+1 < 16) LOADS(ch+1);
    COMPUTE(buf);
    if (ch+1 < 16) STORES(buf^1);
    __syncthreads();
  }
  // split-K reduction (32-way over kg) + epilogue
  float* red = sm + S_RED;
  #pragma unroll
  for (int i=0;i<8;++i){
    #pragma unroll
    for (int j=0;j<4;++j) red[tid*33 + i*4 + j] = acc[i][j];
  }
  __syncthreads();
  {
    const int o = tid;                  // 512 outputs: 64r x 8n
    const int r = o >> 3, nl = o & 7;
    float sum = 0.f;
    #pragma unroll
    for (int kk=0;kk<32;++kk)
      sum += red[((r>>3) + 8*(nl>>2) + 16*kk)*33 + (r&7)*4 + (nl&3)];
    const int n = n0 + nl;
    const float v = sigf(sum + map_b[n]);
    const unsigned off = (unsigned)(r0 + r)*512u + (unsigned)n;
    XM[off] = v;
    outp_t[off] = v;
  }
}

// ---------- phase: lstm layer GEMM + cell ----------
// 512 thr: rg=tid&7, ng=(tid>>3)&7 (8 col-groups of 4), kg=tid>>6 (8 k-slices of 16)
__device__ __forceinline__ void lstm_phase(float* sm, const int l,
    const float* __restrict__ WL, const float* __restrict__ xs,
    const float* __restrict__ FCc, float* __restrict__ FCn,
    float* __restrict__ X0, const float* __restrict__ bih, const float* __restrict__ bhh,
    int tid, int r0, int cb)
{
  const int rg = tid & 7;
  const int ng = (tid >> 3) & 7;
  const int kg = tid >> 6;
  const int c0 = cb * 32;
  float acc[8][4];
  #pragma unroll
  for (int i=0;i<8;++i){
    #pragma unroll
    for (int j=0;j<4;++j) acc[i][j]=0.f;
  }
  float4 va[4], vw4[2];

  auto LOADS = [&](int ch){
    if (ch < 4){                                     // x part (k<512)
      #pragma unroll
      for (int it=0; it<4; ++it){
        const int e = tid + it*512, r = e>>5, kq = e&31;
        va[it] = *(const float4*)&xs[(unsigned)(r0+r)*512u + (unsigned)(ch*128 + kq*4)];
      }
    } else {                                         // h part from FCIN map layout
      #pragma unroll
      for (int it=0; it<4; ++it){
        const int e = tid + it*512, r = e>>5, kq = e&31;
        const int b = r0 + r;
        const unsigned q = (unsigned)((ch-4)*128 + kq*4);
        va[it] = *(const float4*)&FCc[(unsigned)((l<<7) + (b>>1))*2048u + (unsigned)(b&1)*1024u + q];
      }
    }
    #pragma unroll
    for (int it=0; it<2; ++it){
      const int e = tid + it*512, n = e>>5, kq = e&31;
      vw4[it] = *(const float4*)&WL[(unsigned)(c0+n)*1024u + (unsigned)(ch*128 + kq*4)];
    }
  };
  auto STORES = [&](int buf){
    float* A_ = sm + (buf ? S_AS1 : S_AS0);
    float* W_ = sm + (buf ? S_WS1 : S_WS0);
    #pragma unroll
    for (int it=0; it<4; ++it){
      const int e = tid + it*512, r = e>>5, kq = e&31;
      const int col = r ^ ((kq&7)<<2);
      A_[(kq*4+0)*68 + col] = va[it].x;
      A_[(kq*4+1)*68 + col] = va[it].y;
      A_[(kq*4+2)*68 + col] = va[it].z;
      A_[(kq*4+3)*68 + col] = va[it].w;
    }
    #pragma unroll
    for (int it=0; it<2; ++it){
      const int e = tid + it*512, n = e>>5, kq = e&31;
      const int col = n ^ ((kq&7)<<2);
      W_[(kq*4+0)*36 + col] = vw4[it].x;
      W_[(kq*4+1)*36 + col] = vw4[it].y;
      W_[(kq*4+2)*36 + col] = vw4[it].z;
      W_[(kq*4+3)*36 + col] = vw4[it].w;
    }
  };
  auto COMPUTE = [&](int buf){
    const float* A_ = sm + (buf ? S_AS1 : S_AS0);
    const float* W_ = sm + (buf ? S_WS1 : S_WS0);
    #pragma unroll
    for (int u=0; u<16; ++u){
      const int k = kg*16 + u;
      const int s = (((kg<<2) + (u>>2)) & 7) << 2;  // phi(k)
      const int ca = (rg*8) ^ s;
      const int cw = (ng*4) ^ s;
      const float4 a0 = *(const float4*)&A_[k*68 + ca];
      const float4 a1 = *(const float4*)&A_[k*68 + (ca^4)];
      const float4 w0 = *(const float4*)&W_[k*36 + cw];
      fma8x4(acc, a0, a1, w0);
    }
  };

  LOADS(0); STORES(1);
  __syncthreads();
  #pragma unroll 1
  for (int ch = 0; ch < 8; ++ch){
    const int buf = (ch & 1) ^ 1;
    if (ch+1 < 8) LOADS(ch+1);
    COMPUTE(buf);
    if (ch+1 < 8) STORES(buf^1);
    __syncthreads();
  }

  // split-K reduction (8-way over kg) -> gate exchange
  float* red = sm + S_RED;
  float* gs  = sm + S_GS;
  #pragma unroll
  for (int i=0;i<8;++i){
    #pragma unroll
    for (int j=0;j<4;++j) red[tid*33 + i*4 + j] = acc[i][j];
  }
  __syncthreads();
  #pragma unroll
  for (int s=0;s<4;++s){
    const int o = tid + s*512;          // 2048 outputs: 64r x 32c
    const int r = o >> 5, c = o & 31;
    float sum = 0.f;
    #pragma unroll
    for (int kk=0;kk<8;++kk)
      sum += red[((r>>3) + 8*(c>>2) + 64*kk)*33 + (r&7)*4 + (c&3)];
    gs[c*65 + r] = sum;
  }
  __syncthreads();
  // cell update: one (row, j) state per thread (64 rows x 8 j = 512)
  const int r = tid & 63, j0 = tid >> 6;
  const int row = r0 + r;
  const unsigned srow = (unsigned)((l<<7) + (row>>1))*2048u + (unsigned)(row&1)*1024u;
  const int jg = cb*8 + j0;
  const float gi = gs[(j0*4+0)*65 + r] + bih[jg]       + bhh[jg];
  const float gf = gs[(j0*4+1)*65 + r] + bih[512+jg]   + bhh[512+jg];
  const float gg = gs[(j0*4+2)*65 + r] + bih[1024+jg]  + bhh[1024+jg];
  const float go = gs[(j0*4+3)*65 + r] + bih[1536+jg]  + bhh[1536+jg];
  const float cp = FCc[srow + 512u + (unsigned)jg];
  const float c2 = sigf(gf)*cp + sigf(gi)*tanhf_(gg);
  const float h2 = sigf(go)*tanhf_(c2);
  if (l == 0) X0[(unsigned)row*512u + (unsigned)jg] = h2;   // raw h2 feeds layer 1
  FCn[srow + (unsigned)jg]        = tanhf_(h2);             // carried h (tanh)
  FCn[srow + 512u + (unsigned)jg] = tanhf_(c2);             // carried c (tanh)
}

// ---------- persistent cooperative kernel: whole 256-step sequence ----------
// 512 thr = 8 waves = 2 waves/SIMD IF VGPR<=256. R7's (512,2) capped VGPR at 128 ->
// spills (WRITE_SIZE x10). (512,1) lets allocator take ~150-200: no spill, still
// 2 waves/SIMD at runtime since <=256.
__launch_bounds__(512, 1)
__global__ void persist(const float* __restrict__ map_w, const float* __restrict__ map_b,
                        const float* __restrict__ bih0, const float* __restrict__ bhh0,
                        const float* __restrict__ bih1, const float* __restrict__ bhh1,
                        float* __restrict__ ws, float* __restrict__ outp)
{
  __shared__ float sm[S_TOT];
  const int tid = threadIdx.x;
  const int blk = blockIdx.x;
  // XCD-aware swizzle: per-XCD weight slice = 8 cb x (64+128+128)KB = 2.56MB < 4MB L2.
  const int cb = ((blk & 7) << 3) | ((blk >> 3) & 7);
  const int rb = blk >> 6;
  const int r0 = rb * 64;
  float* FC = ws + OFF_FC;
  float* XM = ws + OFF_XM;
  float* X0 = ws + OFF_X0;
  unsigned* arr = (unsigned*)(ws + OFF_ARR);
  unsigned nsync = 0;

  #pragma unroll 1
  for (int t = 0; t < SEQ; ++t){
    const unsigned cur = (unsigned)(t & 1);
    const float* FCc = FC + cur*524288u;
    float* FCn = FC + (cur^1u)*524288u;

    map_phase(sm, FCc, map_w, map_b, XM, outp + (size_t)t*131072u, tid, r0, cb);
    if (t == SEQ-1) break;                       // last step only needs the map output
    gsync(arr, ++nsync, tid, blk);
    lstm_phase(sm, 0, ws + WL0, XM, FCc, FCn, X0, bih0, bhh0, tid, r0, cb);
    gsync(arr, ++nsync, tid, blk);
    lstm_phase(sm, 1, ws + WL1, X0, FCc, FCn, X0, bih1, bhh1, tid, r0, cb);
    gsync(arr, ++nsync, tid, blk);
  }
}

extern "C" void kernel_launch(void* const* d_in, const int* in_sizes, int n_in,
                              void* d_out, int out_size, void* d_ws, size_t ws_size,
                              hipStream_t stream)
{
  (void)in_sizes; (void)n_in; (void)out_size; (void)ws_size;
  const float* latent = (const float*)d_in[0];
  const float* fc_w   = (const float*)d_in[1];
  const float* fc_b   = (const float*)d_in[2];
  const float* map_w  = (const float*)d_in[3];
  const float* map_b  = (const float*)d_in[4];
  const float* wih0   = (const float*)d_in[5];
  const float* whh0   = (const float*)d_in[6];
  const float* bih0   = (const float*)d_in[7];
  const float* bhh0   = (const float*)d_in[8];
  const float* wih1   = (const float*)d_in[9];
  const float* whh1   = (const float*)d_in[10];
  const float* bih1   = (const float*)d_in[11];
  const float* bhh1   = (const float*)d_in[12];
  float* ws = (float*)d_ws;
  float* outp = (float*)d_out;

  tr_kernel<<<2048,256,0,stream>>>(fc_w, ws + FCT, 2048, 256);
  wprep<<<16384,256,0,stream>>>(wih0, whh0, wih1, whh1, ws);
  init2<<<256,256,0,stream>>>(latent, fc_b, ws);

  void* args[8];
  args[0] = (void*)&map_w; args[1] = (void*)&map_b;
  args[2] = (void*)&bih0;  args[3] = (void*)&bhh0;
  args[4] = (void*)&bih1;  args[5] = (void*)&bhh1;
  args[6] = (void*)&ws;    args[7] = (void*)&outp;
  hipError_t e = hipLaunchCooperativeKernel((const void*)persist, dim3(256), dim3(512),
                                            args, 0, stream);
  if (e != hipSuccess){
    persist<<<dim3(256), dim3(512), 0, stream>>>(map_w, map_b, bih0, bhh0,
                                                 bih1, bhh1, ws, outp);
  }
}

// Round 14
// 32813.171 us; speedup vs baseline: 1.6003x; 1.5989x over previous
//
#include <hip/hip_runtime.h>

#define SEQ 256

// ---- ws layout (float offsets) ----
#define WL0     0u           // lstm0 fused W' [c=j*4+g][k=1024] (k<512: wih, else whh)
#define WL1     2097152u     // lstm1 fused W'
#define FCT     4194304u     // fc_w^T [k=256][n=2048]
#define OFF_FC  4718592u     // FCIN double buffer [2][256][2048] (map layout)
#define OFF_XM  5767168u     // sigmoid(map) [256][512]
#define OFF_X0  5898240u     // raw h2 of layer0 [256][512]
#define OFF_ARR 6029312u     // flag-array barrier: 512 slots x 32-u32 stride (128B)
// end 6045696 floats = 24.2 MB

// ---- LDS float offsets (256-thr, 32-row tiles, BK=64) ----
// A tile: [64 k][36], col = c ^ phi(k), phi(k) = ((k>>2)&7)<<2 ; W tile: [64 k][36]
#define S_AS0 0
#define S_WS0 2304
#define S_AS1 4608
#define S_WS1 6912           // ends 9216
#define S_RED 9216           // 256*33 = 8448 split-K partials (independent region)
#define S_GS  17664          // 32*33 = 1056 gate exchange
#define S_TOT 18720          // 74880 B -> 2 blocks/CU (149.8 KB/CU <= 160 KB)

__device__ __forceinline__ float sigf(float x){ return 1.0f/(1.0f + __expf(-x)); }
__device__ __forceinline__ float tanhf_(float x){
  float cx = fminf(fmaxf(x, -15.f), 15.f);
  float e = __expf(2.f*cx);
  return (e-1.f)/(e+1.f);
}

// ---------- one-time: transpose fc_w -> FCT[k][n] ----------
__global__ __launch_bounds__(256) void tr_kernel(const float* __restrict__ src,
                                                 float* __restrict__ dst, int R, int C){
  int i = blockIdx.x*256 + threadIdx.x;
  if (i < R*C){ int r = i / C, c = i - r*C; dst[(size_t)c*R + r] = src[i]; }
}

// ---------- one-time: build fused gate-interleaved LSTM weights ----------
__global__ __launch_bounds__(256) void wprep(const float* __restrict__ wih0,
                                             const float* __restrict__ whh0,
                                             const float* __restrict__ wih1,
                                             const float* __restrict__ whh1,
                                             float* __restrict__ ws){
  const unsigned idx = blockIdx.x*256u + threadIdx.x;
  const unsigned layer = idx >> 21, rem = idx & 2097151u;
  const unsigned c = rem >> 10, k = rem & 1023u;
  const unsigned j = c >> 2, g = c & 3u;
  const float* wih = layer ? wih1 : wih0;
  const float* whh = layer ? whh1 : whh0;
  const float v = (k < 512u) ? wih[(g*512u + j)*512u + k] : whh[(g*512u + j)*512u + (k - 512u)];
  ws[(layer ? WL1 : WL0) + rem] = v;
}

// ---------- init: dec=tanh(latent@fc_w.T+fc_b) scattered into FCIN[0] map layout ----------
__global__ __launch_bounds__(256) void init2(const float* __restrict__ latent,
                                             const float* __restrict__ fc_b,
                                             float* __restrict__ ws){
  __shared__ float ls[256];
  const int b = blockIdx.x, tid = threadIdx.x;
  // zero 512 barrier slots (each of 256 init-blocks zeros 2 slots)
  if (tid < 32){
    __hip_atomic_store((unsigned*)(ws + OFF_ARR) + b*32 + tid, 0u,
                       __ATOMIC_RELAXED, __HIP_MEMORY_SCOPE_AGENT);
    __hip_atomic_store((unsigned*)(ws + OFF_ARR) + (b+256)*32 + tid, 0u,
                       __ATOMIC_RELAXED, __HIP_MEMORY_SCOPE_AGENT);
  }
  ls[tid] = latent[b*256 + tid];
  __syncthreads();
  const float* fT = ws + FCT;
  for (int nc = 0; nc < 8; ++nc){
    const int n = nc*256 + tid;
    float acc = fc_b[n];
    for (int k = 0; k < 256; ++k) acc += ls[k] * fT[k*2048 + n];
    const float v = tanhf_(acc);
    const unsigned f = (unsigned)b*2048u + (unsigned)n;
    const unsigned l = f >> 18, p = (f >> 10) & 255u, q = f & 1023u;
    ws[OFF_FC + (l*128u + (p>>1))*2048u + (p&1u)*1024u + q] = v;
  }
}

// ---------- flag-array grid barrier (R4-proven protocol, 512 slots) ----------
__device__ __forceinline__ void gsync(unsigned* arr, unsigned epoch, int tid, int blk){
  __syncthreads();                       // all waves' stores drained (vmcnt 0)
  if (tid == 0)
    __hip_atomic_store(arr + (unsigned)blk*32u, epoch,
                       __ATOMIC_RELEASE, __HIP_MEMORY_SCOPE_AGENT);
  if (tid < 64){
    unsigned m;
    do {
      m = 0xFFFFFFFFu;
      #pragma unroll
      for (int q = 0; q < 8; ++q){
        const unsigned v = __hip_atomic_load(arr + (unsigned)(tid + 64*q)*32u,
                                             __ATOMIC_RELAXED, __HIP_MEMORY_SCOPE_AGENT);
        m = v < m ? v : m;
      }
      if (m < epoch) __builtin_amdgcn_s_sleep(2);
    } while (!__all(m >= epoch));
  }
  __syncthreads();
  if (tid == 0) __builtin_amdgcn_fence(__ATOMIC_ACQUIRE, "agent");   // one inv per block
  __syncthreads();
}

__device__ __forceinline__ void fma8x4(float acc[8][4], const float4 A0, const float4 A1,
                                       const float4 W0){
  const float a_[8] = {A0.x,A0.y,A0.z,A0.w,A1.x,A1.y,A1.z,A1.w};
  const float w_[4] = {W0.x,W0.y,W0.z,W0.w};
  #pragma unroll
  for (int i=0;i<8;++i)
    #pragma unroll
    for (int j=0;j<4;++j) acc[i][j] = __builtin_fmaf(a_[i], w_[j], acc[i][j]);
}

// ---------- phase: map GEMM out[256,512] = sigmoid(FCIN @ map_w^T + b) ----------
// 256 thr, tile 32r x 8n, K=2048, BK=64: rg=tid&3 (8 rows each), ng=(tid>>2)&1 (4 cols),
// kg=tid>>3 (32 k-slices of 2)
__device__ __forceinline__ void map_phase(float* sm, const float* __restrict__ FCc,
    const float* __restrict__ map_w, const float* __restrict__ map_b,
    float* __restrict__ XM, float* __restrict__ outp_t, int tid, int r0, int cb)
{
  const int rg = tid & 3;
  const int ng = (tid >> 2) & 1;
  const int kg = tid >> 3;
  const int n0 = cb * 8;
  float acc[8][4];
  #pragma unroll
  for (int i=0;i<8;++i){
    #pragma unroll
    for (int j=0;j<4;++j) acc[i][j]=0.f;
  }
  float4 va[2]; float4 vw;

  auto LOADS = [&](int ch){
    #pragma unroll
    for (int it=0; it<2; ++it){
      const int e = tid + it*256, r = e>>4, kq = e&15;
      va[it] = *(const float4*)&FCc[(unsigned)(r0+r)*2048u + (unsigned)(ch*64 + kq*4)];
    }
    if (tid < 128){ const int n = tid>>4, kq = tid&15;
      vw = *(const float4*)&map_w[(unsigned)(n0+n)*2048u + (unsigned)(ch*64 + kq*4)]; }
  };
  auto STORES = [&](int buf){
    float* A_ = sm + (buf ? S_AS1 : S_AS0);
    float* W_ = sm + (buf ? S_WS1 : S_WS0);
    #pragma unroll
    for (int it=0; it<2; ++it){
      const int e = tid + it*256, r = e>>4, kq = e&15;
      const int col = r ^ ((kq&7)<<2);           // phi(k)=((k>>2)&7)<<2, k=4kq+u
      A_[(kq*4+0)*36 + col] = va[it].x;
      A_[(kq*4+1)*36 + col] = va[it].y;
      A_[(kq*4+2)*36 + col] = va[it].z;
      A_[(kq*4+3)*36 + col] = va[it].w;
    }
    if (tid < 128){ const int n = tid>>4, kq = tid&15;
      const int col = n ^ ((kq&7)<<2);
      W_[(kq*4+0)*36 + col] = vw.x;
      W_[(kq*4+1)*36 + col] = vw.y;
      W_[(kq*4+2)*36 + col] = vw.z;
      W_[(kq*4+3)*36 + col] = vw.w; }
  };
  auto COMPUTE = [&](int buf){
    const float* A_ = sm + (buf ? S_AS1 : S_AS0);
    const float* W_ = sm + (buf ? S_WS1 : S_WS0);
    #pragma unroll
    for (int u=0; u<2; ++u){
      const int k = kg*2 + u;
      const int phi = ((k>>2)&7)<<2;
      const int ca0 = (rg*8) ^ phi;
      const float4 a0 = *(const float4*)&A_[k*36 + ca0];
      const float4 a1 = *(const float4*)&A_[k*36 + (ca0^4)];
      const float4 w0 = *(const float4*)&W_[k*36 + ((ng*4) ^ phi)];
      fma8x4(acc, a0, a1, w0);
    }
  };

  LOADS(0); STORES(1);
  __syncthreads();
  #pragma unroll 1
  for (int ch = 0; ch < 32; ++ch){
    const int buf = (ch & 1) ^ 1;
    if (ch+1 < 32) LOADS(ch+1);
    COMPUTE(buf);
    if (ch+1 < 32) STORES(buf^1);
    __syncthreads();
  }
  // split-K reduction (32-way over kg) + epilogue
  float* red = sm + S_RED;
  #pragma unroll
  for (int i=0;i<8;++i){
    #pragma unroll
    for (int j=0;j<4;++j) red[tid*33 + i*4 + j] = acc[i][j];
  }
  __syncthreads();
  {
    const int r = tid >> 3, nl = tid & 7;    // 256 outputs: 32r x 8n
    float sum = 0.f;
    #pragma unroll
    for (int kk=0;kk<32;++kk)
      sum += red[((r>>3) + 4*(nl>>2) + 8*kk)*33 + (r&7)*4 + (nl&3)];
    const int n = n0 + nl;
    const float v = sigf(sum + map_b[n]);
    const unsigned off = (unsigned)(r0 + r)*512u + (unsigned)n;
    XM[off] = v;
    outp_t[off] = v;
  }
}

// ---------- phase: lstm layer GEMM + cell ----------
// 256 thr, tile 32r x 32c (8 j x 4 gates), K=1024, BK=64: rg=tid&3, ng=(tid>>2)&7,
// kg=tid>>5 (8 k-slices of 8)
__device__ __forceinline__ void lstm_phase(float* sm, const int l,
    const float* __restrict__ WL, const float* __restrict__ xs,
    const float* __restrict__ FCc, float* __restrict__ FCn,
    float* __restrict__ X0, const float* __restrict__ bih, const float* __restrict__ bhh,
    int tid, int r0, int cb)
{
  const int rg = tid & 3;
  const int ng = (tid >> 2) & 7;
  const int kg = tid >> 5;
  const int c0 = cb * 32;
  float acc[8][4];
  #pragma unroll
  for (int i=0;i<8;++i){
    #pragma unroll
    for (int j=0;j<4;++j) acc[i][j]=0.f;
  }
  float4 va[2], vw4[2];

  auto LOADS = [&](int ch){
    if (ch < 8){                                     // x part (k<512)
      #pragma unroll
      for (int it=0; it<2; ++it){
        const int e = tid + it*256, r = e>>4, kq = e&15;
        va[it] = *(const float4*)&xs[(unsigned)(r0+r)*512u + (unsigned)(ch*64 + kq*4)];
      }
    } else {                                         // h part from FCIN map layout
      #pragma unroll
      for (int it=0; it<2; ++it){
        const int e = tid + it*256, r = e>>4, kq = e&15;
        const int b = r0 + r;
        const unsigned q = (unsigned)((ch-8)*64 + kq*4);
        va[it] = *(const float4*)&FCc[(unsigned)((l<<7) + (b>>1))*2048u + (unsigned)(b&1)*1024u + q];
      }
    }
    #pragma unroll
    for (int it=0; it<2; ++it){
      const int e = tid + it*256, n = e>>4, kq = e&15;
      vw4[it] = *(const float4*)&WL[(unsigned)(c0+n)*1024u + (unsigned)(ch*64 + kq*4)];
    }
  };
  auto STORES = [&](int buf){
    float* A_ = sm + (buf ? S_AS1 : S_AS0);
    float* W_ = sm + (buf ? S_WS1 : S_WS0);
    #pragma unroll
    for (int it=0; it<2; ++it){
      const int e = tid + it*256, r = e>>4, kq = e&15;
      const int col = r ^ ((kq&7)<<2);
      A_[(kq*4+0)*36 + col] = va[it].x;
      A_[(kq*4+1)*36 + col] = va[it].y;
      A_[(kq*4+2)*36 + col] = va[it].z;
      A_[(kq*4+3)*36 + col] = va[it].w;
    }
    #pragma unroll
    for (int it=0; it<2; ++it){
      const int e = tid + it*256, n = e>>4, kq = e&15;
      const int col = n ^ ((kq&7)<<2);
      W_[(kq*4+0)*36 + col] = vw4[it].x;
      W_[(kq*4+1)*36 + col] = vw4[it].y;
      W_[(kq*4+2)*36 + col] = vw4[it].z;
      W_[(kq*4+3)*36 + col] = vw4[it].w;
    }
  };
  auto COMPUTE = [&](int buf){
    const float* A_ = sm + (buf ? S_AS1 : S_AS0);
    const float* W_ = sm + (buf ? S_WS1 : S_WS0);
    #pragma unroll
    for (int u=0; u<8; ++u){
      const int k = kg*8 + u;
      const int phi = ((k>>2)&7)<<2;
      const int ca0 = (rg*8) ^ phi;
      const float4 a0 = *(const float4*)&A_[k*36 + ca0];
      const float4 a1 = *(const float4*)&A_[k*36 + (ca0^4)];
      const float4 w0 = *(const float4*)&W_[k*36 + ((ng*4) ^ phi)];
      fma8x4(acc, a0, a1, w0);
    }
  };

  LOADS(0); STORES(1);
  __syncthreads();
  #pragma unroll 1
  for (int ch = 0; ch < 16; ++ch){
    const int buf = (ch & 1) ^ 1;
    if (ch+1 < 16) LOADS(ch+1);
    COMPUTE(buf);
    if (ch+1 < 16) STORES(buf^1);
    __syncthreads();
  }

  // split-K reduction (8-way over kg) -> gate exchange
  float* red = sm + S_RED;
  float* gs  = sm + S_GS;
  #pragma unroll
  for (int i=0;i<8;++i){
    #pragma unroll
    for (int j=0;j<4;++j) red[tid*33 + i*4 + j] = acc[i][j];
  }
  __syncthreads();
  #pragma unroll
  for (int s=0;s<4;++s){
    const int o = tid + s*256;          // 1024 sums: 32r x 32c
    const int r = o >> 5, c = o & 31;
    float sum = 0.f;
    #pragma unroll
    for (int kk=0;kk<8;++kk)
      sum += red[((r>>3) + 4*(c>>2) + 32*kk)*33 + (r&7)*4 + (c&3)];
    gs[c*33 + r] = sum;
  }
  __syncthreads();
  // cell update: one (row, j) state per thread (32 rows x 8 j = 256)
  const int r = tid & 31, j0 = tid >> 5;
  const int row = r0 + r;
  const unsigned srow = (unsigned)((l<<7) + (row>>1))*2048u + (unsigned)(row&1)*1024u;
  const int jg = cb*8 + j0;
  const float gi = gs[(j0*4+0)*33 + r] + bih[jg]       + bhh[jg];
  const float gf = gs[(j0*4+1)*33 + r] + bih[512+jg]   + bhh[512+jg];
  const float gg = gs[(j0*4+2)*33 + r] + bih[1024+jg]  + bhh[1024+jg];
  const float go = gs[(j0*4+3)*33 + r] + bih[1536+jg]  + bhh[1536+jg];
  const float cp = FCc[srow + 512u + (unsigned)jg];
  const float c2 = sigf(gf)*cp + sigf(gi)*tanhf_(gg);
  const float h2 = sigf(go)*tanhf_(c2);
  if (l == 0) X0[(unsigned)row*512u + (unsigned)jg] = h2;   // raw h2 feeds layer 1
  FCn[srow + (unsigned)jg]        = tanhf_(h2);             // carried h (tanh)
  FCn[srow + 512u + (unsigned)jg] = tanhf_(c2);             // carried c (tanh)
}

// ---------- persistent cooperative kernel: whole 256-step sequence ----------
// 512 blocks x 256 thr, 74.9KB LDS -> 2 blocks/CU, 8 waves/CU = 2 waves/SIMD.
// Per-thread regs ~100 < 128: no spill under any launch-bounds interpretation.
__launch_bounds__(256, 2)
__global__ void persist(const float* __restrict__ map_w, const float* __restrict__ map_b,
                        const float* __restrict__ bih0, const float* __restrict__ bhh0,
                        const float* __restrict__ bih1, const float* __restrict__ bhh1,
                        float* __restrict__ ws, float* __restrict__ outp)
{
  __shared__ float sm[S_TOT];
  const int tid = threadIdx.x;
  const int blk = blockIdx.x;
  // blk = rb*64 + cbl; XCD = blk%8 = cbl%8 (64 = 0 mod 8). Swizzle cbl so each XCD
  // serves cb in {8x..8x+7} for all rb -> per-XCD weight slice 2.56MB (L2-fit).
  const int cbl = blk & 63;
  const int cb = ((cbl & 7) << 3) | (cbl >> 3);
  const int rb = blk >> 6;              // 0..7, 32-row slices
  const int r0 = rb * 32;
  float* FC = ws + OFF_FC;
  float* XM = ws + OFF_XM;
  float* X0 = ws + OFF_X0;
  unsigned* arr = (unsigned*)(ws + OFF_ARR);
  unsigned nsync = 0;

  #pragma unroll 1
  for (int t = 0; t < SEQ; ++t){
    const unsigned cur = (unsigned)(t & 1);
    const float* FCc = FC + cur*524288u;
    float* FCn = FC + (cur^1u)*524288u;

    map_phase(sm, FCc, map_w, map_b, XM, outp + (size_t)t*131072u, tid, r0, cb);
    if (t == SEQ-1) break;                       // last step only needs the map output
    gsync(arr, ++nsync, tid, blk);
    lstm_phase(sm, 0, ws + WL0, XM, FCc, FCn, X0, bih0, bhh0, tid, r0, cb);
    gsync(arr, ++nsync, tid, blk);
    lstm_phase(sm, 1, ws + WL1, X0, FCc, FCn, X0, bih1, bhh1, tid, r0, cb);
    gsync(arr, ++nsync, tid, blk);
  }
}

extern "C" void kernel_launch(void* const* d_in, const int* in_sizes, int n_in,
                              void* d_out, int out_size, void* d_ws, size_t ws_size,
                              hipStream_t stream)
{
  (void)in_sizes; (void)n_in; (void)out_size; (void)ws_size;
  const float* latent = (const float*)d_in[0];
  const float* fc_w   = (const float*)d_in[1];
  const float* fc_b   = (const float*)d_in[2];
  const float* map_w  = (const float*)d_in[3];
  const float* map_b  = (const float*)d_in[4];
  const float* wih0   = (const float*)d_in[5];
  const float* whh0   = (const float*)d_in[6];
  const float* bih0   = (const float*)d_in[7];
  const float* bhh0   = (const float*)d_in[8];
  const float* wih1   = (const float*)d_in[9];
  const float* whh1   = (const float*)d_in[10];
  const float* bih1   = (const float*)d_in[11];
  const float* bhh1   = (const float*)d_in[12];
  float* ws = (float*)d_ws;
  float* outp = (float*)d_out;

  tr_kernel<<<2048,256,0,stream>>>(fc_w, ws + FCT, 2048, 256);
  wprep<<<16384,256,0,stream>>>(wih0, whh0, wih1, whh1, ws);
  init2<<<256,256,0,stream>>>(latent, fc_b, ws);

  void* args[8];
  args[0] = (void*)&map_w; args[1] = (void*)&map_b;
  args[2] = (void*)&bih0;  args[3] = (void*)&bhh0;
  args[4] = (void*)&bih1;  args[5] = (void*)&bhh1;
  args[6] = (void*)&ws;    args[7] = (void*)&outp;
  hipError_t e = hipLaunchCooperativeKernel((const void*)persist, dim3(512), dim3(256),
                                            args, 0, stream);
  if (e != hipSuccess){
    // fallback: 512 blocks x 74.9KB LDS = 2 blocks/CU by construction -> co-resident
    persist<<<dim3(512), dim3(256), 0, stream>>>(map_w, map_b, bih0, bhh0,
                                                 bih1, bhh1, ws, outp);
  }
}